// Round 2
// baseline (91.954 us; speedup 1.0000x reference)
//
#include <hip/hip_runtime.h>

// VideoEmbedding: out[b,f,tok,c]; tok0 = cls (= temp[f]); tok 1..144:
//   mean_{400 px} emb_weight[int(x*255)] + pos[patch] + temp[f]
// Histogram formulation: out[p, n] = (1/400) * sum_k cnt[p][k] * emb[k][n].
// This round: VALU f32 GEMM (no MFMA-layout risk) + runtime dtype detection
// (harness signals conflict: template says f32 inputs, test labels say bf16).

#define F_   20
#define HW   240
#define SEG  20
#define PPB  8            // patches per block
#define BPF  18           // blocks per frame (144/8)
#define NBLK (40 * BPF)   // 720 blocks

__device__ __forceinline__ float bf16_to_f32(ushort u) {
    union { uint i; float f; } c; c.i = ((uint)u) << 16; return c.f;
}
__device__ __forceinline__ ushort f32_to_bf16(float v) {
    union { float f; uint i; } c; c.f = v;
    uint u = c.i;
    u += 0x7FFFu + ((u >> 16) & 1u);   // round-to-nearest-even
    return (ushort)(u >> 16);
}

template<bool BF16> __device__ __forceinline__ float load_in(const void* p, int i) {
    if constexpr (BF16) return bf16_to_f32(((const ushort*)p)[i]);
    else                return ((const float*)p)[i];
}
template<bool BF16> __device__ __forceinline__ void store_out(void* p, int i, float v) {
    if constexpr (BF16) ((ushort*)p)[i] = f32_to_bf16(v);
    else                ((float*)p)[i] = v;
}

// x in [0,1): if stored bf16, every ushort <= 0x3F80 (== 1.0).
// If stored f32, even-index ushorts are low mantissa halves (~uniform 16-bit):
// P(128 samples all <= 0x3F80) ~ 0.25^128 ~ 0.
__global__ void detect_dtype(const ushort* __restrict__ x, int* __restrict__ flag) {
    if (threadIdx.x == 0) {
        int bad = 0;
        for (int i = 0; i < 256; i += 2) bad += (int)(x[i] > 0x3F80u);
        *flag = (bad == 0) ? 1 : 0;   // 1 = bf16, 0 = f32
    }
}

template<bool BF16>
__device__ __forceinline__ void embed_body(
    const void* __restrict__ xg, const void* __restrict__ embg,
    const void* __restrict__ posg, const void* __restrict__ tempg,
    void* __restrict__ outg,
    uint (&cnt)[PPB][256], float (&cntf)[PPB][256])
{
    const int tid  = threadIdx.x;
    const int bf   = blockIdx.x / BPF;   // frame index b*20+f
    const int pblk = blockIdx.x % BPF;
    const int p0   = pblk * PPB;         // base patch within frame
    const int f    = bf % F_;

    // zero histogram
    #pragma unroll
    for (int i = 0; i < PPB; ++i) cnt[i][tid] = 0u;
    __syncthreads();

    // histogram: PPB*400 = 3200 pixels
    const int xbase = bf * (HW * HW);
    for (int it = 0; it < 13; ++it) {
        int i = tid + it * 256;
        if (i < PPB * 400) {
            int p  = i / 400;
            int q  = i - p * 400;
            int gp = p0 + p;
            int pr = gp / 12, pc = gp - pr * 12;
            int qr = q / SEG, qc = q - qr * SEG;
            float xv = load_in<BF16>(xg, xbase + (pr * SEG + qr) * HW + pc * SEG + qc);
            int idx = (int)(xv * 255.0f);          // exact: <=16-bit significand * 255
            idx = idx < 0 ? 0 : (idx > 255 ? 255 : idx);
            atomicAdd(&cnt[p][idx], 1u);
        }
    }
    __syncthreads();

    // counts -> f32
    #pragma unroll
    for (int i = 0; i < PPB; ++i) cntf[i][tid] = (float)cnt[i][tid];
    __syncthreads();

    // GEMM: acc[m] = sum_k cnt[m][k] * emb[k][tid]
    // cntf reads broadcast (same addr across wave); emb reads coalesced, L2-hot.
    float acc[PPB] = {};
    #pragma unroll 4
    for (int k = 0; k < 256; ++k) {
        float e = load_in<BF16>(embg, k * 256 + tid);
        #pragma unroll
        for (int m = 0; m < PPB; ++m) acc[m] += cntf[m][k] * e;
    }

    // epilogue
    const int obase = bf * (145 * 256);
    const float tadd = load_in<BF16>(tempg, f * 256 + tid);
    if (pblk == 0)
        store_out<BF16>(outg, obase + tid, tadd);   // cls = 0 + temp exactly
    #pragma unroll
    for (int m = 0; m < PPB; ++m) {
        int gp = p0 + m;
        float val = acc[m] * (1.0f / 400.0f)
                  + load_in<BF16>(posg, gp * 256 + tid) + tadd;
        store_out<BF16>(outg, obase + (1 + gp) * 256 + tid, val);
    }
}

__global__ __launch_bounds__(256) void video_embed_kernel(
    const void* __restrict__ xg, const void* __restrict__ embg,
    const void* __restrict__ posg, const void* __restrict__ tempg,
    void* __restrict__ outg, const int* __restrict__ flag)
{
    __shared__ uint  cnt[PPB][256];
    __shared__ float cntf[PPB][256];
    const bool isbf = (flag == nullptr) ? true : (*flag != 0);
    if (isbf) embed_body<true >(xg, embg, posg, tempg, outg, cnt, cntf);
    else      embed_body<false>(xg, embg, posg, tempg, outg, cnt, cntf);
}

extern "C" void kernel_launch(void* const* d_in, const int* in_sizes, int n_in,
                              void* d_out, int out_size, void* d_ws, size_t ws_size,
                              hipStream_t stream) {
    int* flag = (ws_size >= sizeof(int)) ? (int*)d_ws : nullptr;
    if (flag)
        detect_dtype<<<dim3(1), dim3(64), 0, stream>>>((const ushort*)d_in[0], flag);
    video_embed_kernel<<<dim3(NBLK), dim3(256), 0, stream>>>(
        d_in[0], d_in[1], d_in[2], d_in[3], d_out, flag);
}

// Round 5
// 91.752 us; speedup vs baseline: 1.0022x; 1.0022x over previous
//
#include <hip/hip_runtime.h>

// VideoEmbedding: out[b,f,tok,c]; tok0 = cls = temp[f];
//   tok 1..144 = (1/400)*sum_px emb_weight[int(x*255)] + pos[patch] + temp[f]
// Histogram x emb GEMM formulation.
// R5: inputs/outputs are f32 (R1/R3/R4's bit-identical absmax 9.5 = three
// correct kernels misreading f32 as bf16; R2 passed via its detector's f32
// path). Keep BOTH dtype paths, detected in-kernel (benign-race shared flag,
// no extra launch). Block = one patch-row (12 patches): pixel strip is fully
// contiguous -> perfectly coalesced vec4 histogram loads (vec4 never straddles
// a patch: 20 % 4 == 0). GEMM: wave owns a 64-wide k-slice, thread owns 4
// channels; wave-uniform ds_read_b128 of counts feeds 4096 MACs; emb read
// exactly once per block; cross-wave partial reduction in LDS.

#define F_   20
#define HW   240
#define SEG  20
#define PPB  12           // patches per block = one patch-row
#define BPF  12           // blocks per frame
#define NBLK (40 * BPF)   // 480 blocks
#define STRIP (HW * SEG)  // 4800 pixels per block

typedef __attribute__((ext_vector_type(4))) float float4_t;

__device__ __forceinline__ float bits_f32(uint u) {
    union { uint i; float f; } c; c.i = u; return c.f;
}
__device__ __forceinline__ float bf16_to_f32(ushort u) { return bits_f32(((uint)u) << 16); }
__device__ __forceinline__ ushort f32_to_bf16(float v) {
    union { float f; uint i; } c; c.f = v;
    uint u = c.i;
    u += 0x7FFFu + ((u >> 16) & 1u);   // round-to-nearest-even
    return (ushort)(u >> 16);
}

// load 4 consecutive input elements as f32
template<bool F32> __device__ __forceinline__ float4_t load4(const void* p, int i) {
    if constexpr (F32) {
        return *(const float4_t*)((const float*)p + i);
    } else {
        ushort4 u = *(const ushort4*)((const ushort*)p + i);
        float4_t r;
        r.x = bf16_to_f32(u.x); r.y = bf16_to_f32(u.y);
        r.z = bf16_to_f32(u.z); r.w = bf16_to_f32(u.w);
        return r;
    }
}
template<bool F32> __device__ __forceinline__ float load1(const void* p, int i) {
    if constexpr (F32) return ((const float*)p)[i];
    else               return bf16_to_f32(((const ushort*)p)[i]);
}
template<bool F32> __device__ __forceinline__ void store1(void* p, int i, float v) {
    if constexpr (F32) ((float*)p)[i] = v;
    else               ((ushort*)p)[i] = f32_to_bf16(v);
}

template<bool F32>
__device__ __forceinline__ void embed_body(
    const void* __restrict__ xg, const void* __restrict__ embg,
    const void* __restrict__ posg, const void* __restrict__ tempg,
    void* __restrict__ outg,
    float (&cntf)[PPB][256], float (&part)[PPB][4][256])
{
    const int tid  = threadIdx.x;
    const int lane = tid & 63;
    const int wave = tid >> 6;
    const int bf   = blockIdx.x / BPF;   // frame index b*20+f
    const int pr   = blockIdx.x % BPF;   // patch row
    const int p0   = pr * 12;            // base patch within frame
    const int f    = bf % F_;

    // ---- histogram: contiguous strip of rows [pr*20, pr*20+20), all 240 cols ----
    const int xbase = bf * (HW * HW) + pr * STRIP;   // element offset, vec4-aligned
    for (int it = 0; it < 5; ++it) {
        int i = tid + it * 256;          // vec4-group index
        if (i < STRIP / 4) {
            int elem = i * 4;
            int col  = elem % HW;        // 4 consecutive cols, same patch (20%4==0)
            int p    = col / SEG;
            float4_t v = load4<F32>(xg, xbase + elem);
            #pragma unroll
            for (int j = 0; j < 4; ++j) {
                int idx = (int)(v[j] * 255.0f);
                idx = idx < 0 ? 0 : (idx > 255 ? 255 : idx);
                atomicAdd(&cntf[p][idx], 1.0f);   // LDS float atomic; counts exact
            }
        }
    }
    __syncthreads();

    // ---- GEMM, k-split by wave: wave w owns k in [w*64, w*64+64) ----
    // thread owns 4 channels n0..n0+3, all 12 patches; acc[12][4] in VGPRs
    const int n0 = lane * 4;
    const int kbase = wave * 64;
    float acc[PPB][4];
    #pragma unroll
    for (int m = 0; m < PPB; ++m)
        #pragma unroll
        for (int c = 0; c < 4; ++c) acc[m][c] = 0.0f;

    #pragma unroll 2
    for (int kq = 0; kq < 16; ++kq) {
        const int k = kbase + kq * 4;
        float e[4][4];
        #pragma unroll
        for (int kk = 0; kk < 4; ++kk) {
            if constexpr (F32) {
                *(float4_t*)(&e[kk][0]) =
                    *(const float4_t*)((const float*)embg + (k + kk) * 256 + n0);
            } else {
                uint2 u = *(const uint2*)((const ushort*)embg + (k + kk) * 256 + n0);
                e[kk][0] = bits_f32(u.x << 16);
                e[kk][1] = bits_f32(u.x & 0xFFFF0000u);
                e[kk][2] = bits_f32(u.y << 16);
                e[kk][3] = bits_f32(u.y & 0xFFFF0000u);
            }
        }
        #pragma unroll
        for (int m = 0; m < PPB; ++m) {
            float4_t c4 = *(const float4_t*)(&cntf[m][k]);   // wave-uniform broadcast
            #pragma unroll
            for (int kk = 0; kk < 4; ++kk)
                #pragma unroll
                for (int c = 0; c < 4; ++c)
                    acc[m][c] += c4[kk] * e[kk][c];
        }
    }

    // ---- per-wave partials -> LDS ----
    #pragma unroll
    for (int m = 0; m < PPB; ++m)
        *(float4_t*)(&part[m][wave][n0]) = *(float4_t*)(&acc[m][0]);
    __syncthreads();

    // ---- reduce 4 waves + epilogue: thread tid owns channel tid ----
    const int obase = bf * (145 * 256);
    const float tadd = load1<F32>(tempg, f * 256 + tid);
    if (pr == 0)
        store1<F32>(outg, obase + tid, tadd);   // cls = 0 + temp exactly
    #pragma unroll
    for (int m = 0; m < PPB; ++m) {
        float s = part[m][0][tid] + part[m][1][tid] + part[m][2][tid] + part[m][3][tid];
        int gp = p0 + m;
        float val = s * (1.0f / 400.0f) + load1<F32>(posg, gp * 256 + tid) + tadd;
        store1<F32>(outg, obase + (1 + gp) * 256 + tid, val);
    }
}

__global__ __launch_bounds__(256) void video_embed_v5_kernel(
    const void* __restrict__ xg, const void* __restrict__ embg,
    const void* __restrict__ posg, const void* __restrict__ tempg,
    void* __restrict__ outg)
{
    __shared__ float cntf[PPB][256];      // 12 KB histogram (float counts)
    __shared__ float part[PPB][4][256];   // 48 KB per-wave partials
    __shared__ int   isf32_s;

    const int tid = threadIdx.x;
    if (tid == 0) isf32_s = 0;
    __syncthreads();

    // zero histogram + dtype detection in one phase.
    // x in [0,1): bf16 ushorts are all <= 0x3F80; f32 low-halves are ~uniform
    // 16-bit (P[128 samples all <= 0x3F80] ~ 0.25^128). Benign race: all
    // writers store 1.
    #pragma unroll
    for (int i = 0; i < PPB; ++i) cntf[i][tid] = 0.0f;
    if (tid < 128 && ((const ushort*)xg)[2 * tid] > 0x3F80u) isf32_s = 1;
    __syncthreads();

    if (isf32_s) embed_body<true >(xg, embg, posg, tempg, outg, cntf, part);
    else         embed_body<false>(xg, embg, posg, tempg, outg, cntf, part);
}

extern "C" void kernel_launch(void* const* d_in, const int* in_sizes, int n_in,
                              void* d_out, int out_size, void* d_ws, size_t ws_size,
                              hipStream_t stream) {
    video_embed_v5_kernel<<<dim3(NBLK), dim3(256), 0, stream>>>(
        d_in[0], d_in[1], d_in[2], d_in[3], d_out);
}

// Round 6
// 86.917 us; speedup vs baseline: 1.0580x; 1.0556x over previous
//
#include <hip/hip_runtime.h>

// VideoEmbedding: out[b,f,tok,c]; tok0 = cls = temp[f];
//   tok 1..144 = (1/400)*sum_px emb_weight[int(x*255)] + pos[patch] + temp[f]
// Histogram x emb GEMM. Inputs proven f32 (R5), but both dtype paths kept via
// in-kernel detection. R6: replace the VALU GEMM (8.4k cyc/wave) with
// mfma_f32_16x16x32_bf16 (~0.5k cyc/wave): prep kernel transposes emb into
// bf16 embT[n][k] in d_ws; main kernel reads A-frags (counts->bf16, exact for
// counts<=256) from LDS via ds_read_b128 and B-frags via L2-hot dwordx4.
// dur_us is dominated by a ~83 us harness floor (two 256 MiB d_ws poison
// fills @ 40.5 us each are the top dispatches); kernel share is ~9 -> ~4 us.

#define F_   20
#define HW   240
#define SEG  20
#define PPB  12           // patches per block = one patch-row
#define BPF  12           // blocks per frame
#define NBLK (40 * BPF)   // 480 blocks
#define STRIP (HW * SEG)  // 4800 pixels per block

typedef __attribute__((ext_vector_type(4))) float float4_t;
typedef __attribute__((ext_vector_type(8))) short short8_t;

__device__ __forceinline__ float bits_f32(uint u) {
    union { uint i; float f; } c; c.i = u; return c.f;
}
__device__ __forceinline__ float bf16_to_f32(ushort u) { return bits_f32(((uint)u) << 16); }
__device__ __forceinline__ ushort f32_to_bf16(float v) {
    union { float f; uint i; } c; c.f = v;
    uint u = c.i;
    u += 0x7FFFu + ((u >> 16) & 1u);   // round-to-nearest-even
    return (ushort)(u >> 16);
}

template<bool F32> __device__ __forceinline__ float4_t load4(const void* p, int i) {
    if constexpr (F32) {
        return *(const float4_t*)((const float*)p + i);
    } else {
        ushort4 u = *(const ushort4*)((const ushort*)p + i);
        float4_t r;
        r.x = bf16_to_f32(u.x); r.y = bf16_to_f32(u.y);
        r.z = bf16_to_f32(u.z); r.w = bf16_to_f32(u.w);
        return r;
    }
}
template<bool F32> __device__ __forceinline__ float load1(const void* p, int i) {
    if constexpr (F32) return ((const float*)p)[i];
    else               return bf16_to_f32(((const ushort*)p)[i]);
}
template<bool F32> __device__ __forceinline__ void store1(void* p, int i, float v) {
    if constexpr (F32) ((float*)p)[i] = v;
    else               ((ushort*)p)[i] = f32_to_bf16(v);
}

// ---------------- prep: embT[n][k] (bf16) = emb[k][n], 64x64 LDS tiles -------
template<bool F32>
__device__ __forceinline__ void prep_body(const void* __restrict__ embg,
                                          ushort* __restrict__ embT,
                                          float (&tile)[64][65])
{
    const int tid = threadIdx.x;
    const int tk  = blockIdx.x & 3;    // k-tile
    const int tn  = blockIdx.x >> 2;   // n-tile
    #pragma unroll
    for (int i = 0; i < 16; ++i) {
        int idx = tid + i * 256, r = idx >> 6, c = idx & 63;
        tile[r][c] = load1<F32>(embg, (tk * 64 + r) * 256 + tn * 64 + c);  // coalesced
    }
    __syncthreads();
    #pragma unroll
    for (int i = 0; i < 16; ++i) {
        int idx = tid + i * 256, r = idx >> 6, c = idx & 63;
        embT[(tn * 64 + r) * 256 + tk * 64 + c] = f32_to_bf16(tile[c][r]); // coalesced k
    }
}

__global__ __launch_bounds__(256) void video_embed_prep_v6(
    const void* __restrict__ xg, const void* __restrict__ embg,
    ushort* __restrict__ embT)
{
    __shared__ float tile[64][65];
    __shared__ int isf32_s;
    const int tid = threadIdx.x;
    if (tid == 0) isf32_s = 0;
    __syncthreads();
    // x in [0,1): bf16 ushorts all <= 0x3F80; f32 low-halves ~uniform 16-bit.
    if (tid < 128 && ((const ushort*)xg)[2 * tid] > 0x3F80u) isf32_s = 1;
    __syncthreads();
    if (isf32_s) prep_body<true >(embg, embT, tile);
    else         prep_body<false>(embg, embT, tile);
}

// ---------------- main: histogram + MFMA + epilogue --------------------------
template<bool F32>
__device__ __forceinline__ void embed_body(
    const void* __restrict__ xg, const ushort* __restrict__ embT,
    const void* __restrict__ posg, const void* __restrict__ tempg,
    void* __restrict__ outg,
    float (&cntf)[PPB][256], ushort (&cntb)[16][264])
{
    const int tid  = threadIdx.x;
    const int lane = tid & 63;
    const int wave = tid >> 6;
    const int bf   = blockIdx.x / BPF;   // frame index b*20+f
    const int pr   = blockIdx.x % BPF;   // patch row
    const int p0   = pr * 12;
    const int f    = bf % F_;

    // ---- histogram over the contiguous 20-row strip (R5-verified) ----
    const int xbase = bf * (HW * HW) + pr * STRIP;
    for (int it = 0; it < 5; ++it) {
        int i = tid + it * 256;
        if (i < STRIP / 4) {
            int elem = i * 4;
            int col  = elem % HW;        // vec4 never straddles a patch (20%4==0)
            int p    = col / SEG;
            float4_t v = load4<F32>(xg, xbase + elem);
            #pragma unroll
            for (int j = 0; j < 4; ++j) {
                int idx = (int)(v[j] * 255.0f);
                idx = idx < 0 ? 0 : (idx > 255 ? 255 : idx);
                atomicAdd(&cntf[p][idx], 1.0f);
            }
        }
    }
    __syncthreads();

    // ---- counts -> bf16 A matrix (rows 12..15 zero-padded) ----
    {
        const int m  = tid >> 4;
        const int c0 = (tid & 15) * 16;
        #pragma unroll
        for (int j = 0; j < 16; ++j) {
            float v = (m < PPB) ? cntf[m][c0 + j] : 0.0f;   // counts <=256 exact
            cntb[m][c0 + j] = f32_to_bf16(v);
        }
    }
    __syncthreads();

    // ---- MFMA: D[16 x 256] = cntb[16 x 256] * emb[256 x 256], wave owns 64 n
    // A-frag: A[m=lane&15][k=quad*8+j]; B-frag: B[k=quad*8+j][n=lane&15];
    // C/D: row=quad*4+reg, col=lane&15 (m89/m91-verified layouts)
    const int am    = lane & 15;
    const int quad  = lane >> 4;
    const int wbase = wave * 64;
    float4_t acc[4] = {{0,0,0,0},{0,0,0,0},{0,0,0,0},{0,0,0,0}};
    #pragma unroll
    for (int s = 0; s < 8; ++s) {                 // k-step of 32
        short8_t a = *(const short8_t*)(&cntb[am][s * 32 + quad * 8]);
        #pragma unroll
        for (int t = 0; t < 4; ++t) {
            short8_t b = *(const short8_t*)(embT + (wbase + t * 16 + am) * 256
                                                 + s * 32 + quad * 8);
            acc[t] = __builtin_amdgcn_mfma_f32_16x16x32_bf16(a, b, acc[t], 0, 0, 0);
        }
    }

    // ---- epilogue ----
    const int obase = bf * (145 * 256);
    if (pr == 0)
        store1<F32>(outg, obase + tid, load1<F32>(tempg, f * 256 + tid)); // cls
    #pragma unroll
    for (int t = 0; t < 4; ++t) {
        #pragma unroll
        for (int r = 0; r < 4; ++r) {
            int m = quad * 4 + r;
            if (m < PPB) {
                int gp = p0 + m;
                int n  = wbase + t * 16 + am;
                float val = acc[t][r] * (1.0f / 400.0f)
                          + load1<F32>(posg, gp * 256 + n)
                          + load1<F32>(tempg, f * 256 + n);
                store1<F32>(outg, obase + (1 + gp) * 256 + n, val);
            }
        }
    }
}

__global__ __launch_bounds__(256) void video_embed_v6_kernel(
    const void* __restrict__ xg, const ushort* __restrict__ embT,
    const void* __restrict__ posg, const void* __restrict__ tempg,
    void* __restrict__ outg)
{
    __shared__ float cntf[PPB][256];                  // 12 KB
    __shared__ __align__(16) ushort cntb[16][264];    // 8.25 KB, row stride 528B (16B-mult)
    __shared__ int isf32_s;

    const int tid = threadIdx.x;
    if (tid == 0) isf32_s = 0;
    __syncthreads();
    #pragma unroll
    for (int i = 0; i < PPB; ++i) cntf[i][tid] = 0.0f;
    if (tid < 128 && ((const ushort*)xg)[2 * tid] > 0x3F80u) isf32_s = 1;
    __syncthreads();

    if (isf32_s) embed_body<true >(xg, embT, posg, tempg, outg, cntf, cntb);
    else         embed_body<false>(xg, embT, posg, tempg, outg, cntf, cntb);
}

extern "C" void kernel_launch(void* const* d_in, const int* in_sizes, int n_in,
                              void* d_out, int out_size, void* d_ws, size_t ws_size,
                              hipStream_t stream) {
    ushort* embT = (ushort*)d_ws;   // 128 KB of the workspace
    video_embed_prep_v6<<<dim3(16), dim3(256), 0, stream>>>(d_in[0], d_in[1], embT);
    video_embed_v6_kernel<<<dim3(NBLK), dim3(256), 0, stream>>>(
        d_in[0], embT, d_in[2], d_in[3], d_out);
}